// Round 6
// baseline (215.684 us; speedup 1.0000x reference)
//
#include <hip/hip_runtime.h>

// logsparseAttention == plain CAUSAL attention (no scale) at L=2048, SUB_LEN=5.
// Q,K,V [B,L,H,D] fp32; Out [B,H,L,D] fp32.  B=4, L=2048, H=16, D=64.
// R6: LDS-amortized flash attention. R5 was LDS-pipe-bound (~74 of 86 us on
// ds_read/write). Each wave now owns 64 queries (4 qcols): K/V fragments are
// read from LDS ONCE per tile into registers and reused by all 4 qcols ->
// LDS cycles/query drop 13.5 -> 6. Blocks: 256 thr / 4 waves, waves 0-1 on
// 128-q supertile pr, waves 2-3 on 15-pr => every block = 66 compute
// wave-tiles (mapping-proof balance). VGPR ~220 -> 2 waves/SIMD (by design;
// kernel is LDS-throughput-bound, not latency-bound).

typedef __attribute__((ext_vector_type(8))) short short8;
typedef __attribute__((ext_vector_type(4))) float floatx4;
typedef _Float16 half8 __attribute__((ext_vector_type(8)));
typedef _Float16 half4 __attribute__((ext_vector_type(4)));

#define NB 4
#define NL 2048
#define NH 16
#define ND 64
#define PADK 72   // halves; 144B row stride
#define PADQ 72

static __device__ __forceinline__ unsigned short f2bf(float f) {
    unsigned int u = __float_as_uint(f);
    u += 0x7fff + ((u >> 16) & 1);
    return (unsigned short)(u >> 16);
}
static __device__ __forceinline__ float bf2f(unsigned short h) {
    return __uint_as_float(((unsigned int)h) << 16);
}

// ---- fused prepass: K -> Kf [bh][key][d] fp16; V -> Vt [bh][d][key] fp16 ----
__global__ __launch_bounds__(256)
void conv_kv(const float* __restrict__ Kg, const float* __restrict__ Vg,
             _Float16* __restrict__ Kf, _Float16* __restrict__ Vt) {
    __shared__ float tile[64][65];
    const int kt = blockIdx.x;       // key tile 0..31
    const int bh = blockIdx.y;       // 0..63
    const int b  = bh >> 4, h = bh & 15;
    const int t  = threadIdx.x;
    const int row = t >> 2;          // 0..63
    const int seg = (t & 3) * 16;    // 0..48
    const size_t gsrc = (((size_t)(b * NL + kt * 64 + row) * NH + h) << 6) + seg;
    {   // K: straight vectorized convert
        float kv[16];
        #pragma unroll
        for (int i = 0; i < 16; i += 4) *(float4*)(kv + i) = *(const float4*)(Kg + gsrc + i);
        half8 o0, o1;
        #pragma unroll
        for (int j2 = 0; j2 < 8; ++j2) { o0[j2] = (_Float16)kv[j2]; o1[j2] = (_Float16)kv[8 + j2]; }
        _Float16* kd = Kf + (((size_t)(bh * NL + kt * 64 + row)) << 6) + seg;
        *(half8*)kd = o0;
        *(half8*)(kd + 8) = o1;
    }
    {   // V phase 1: fp32 tile into LDS
        #pragma unroll
        for (int i = 0; i < 16; i += 4) {
            float4 v = *(const float4*)(Vg + gsrc + i);
            tile[row][seg + i + 0] = v.x;
            tile[row][seg + i + 1] = v.y;
            tile[row][seg + i + 2] = v.z;
            tile[row][seg + i + 3] = v.w;
        }
    }
    __syncthreads();
    #pragma unroll
    for (int pass = 0; pass < 2; ++pass) {   // V phase 2: transpose out as fp16
        const int d  = pass * 32 + (t >> 3);
        const int kk = (t & 7) * 8;
        half8 o;
        #pragma unroll
        for (int j2 = 0; j2 < 8; ++j2) o[j2] = (_Float16)tile[kk + j2][d];
        *(half8*)(Vt + (((size_t)(bh * 64 + d)) << 11) + kt * 64 + kk) = o;
    }
}

// ------------------------------- main kernel --------------------------------
__global__ __launch_bounds__(256, 2)
void lsattn_main(const float* __restrict__ Qg,
                 const _Float16* __restrict__ Kf,
                 const _Float16* __restrict__ Vt,
                 float* __restrict__ Og) {
    __shared__ alignas(16) _Float16 Ks[64 * PADK];       // [key][d]
    __shared__ alignas(16) _Float16 Vs[64 * PADK];       // [d][key]
    __shared__ alignas(16) _Float16 Ps[4 * 16 * PADQ];   // per-wave P [q][key]

    const int id   = (int)blockIdx.x;        // 0..511
    const int bh   = id & 63;
    const int pr   = id >> 6;                // 0..7
    const int tid  = threadIdx.x;
    const int lane = tid & 63;
    const int w    = tid >> 6;               // wave 0..3
    const int col  = lane & 15;
    const int quad = lane >> 4;

    // wave's 64-query tile: waves 0-1 -> supertile pr, waves 2-3 -> 15-pr
    const int base128 = (w < 2) ? pr : (15 - pr);
    const int qbase   = base128 * 128 + (w & 1) * 64;
    const int sa      = qbase >> 6;          // wave's last key tile

    // Q fragments for 4 qcols, B-operand layout:
    // lane holds Q[qbase + qc*16 + col][c*32 + quad*8 + j]
    half8 qf[4][2];
    #pragma unroll
    for (int qc = 0; qc < 4; ++qc) {
        const float* qp = Qg + (((size_t)((bh >> 4) * NL + qbase + qc * 16 + col) * NH + (bh & 15)) << 6) + quad * 8;
        #pragma unroll
        for (int c = 0; c < 2; ++c) {
            float4 a = *(const float4*)(qp + c * 32);
            float4 b = *(const float4*)(qp + c * 32 + 4);
            qf[qc][c][0] = (_Float16)a.x; qf[qc][c][1] = (_Float16)a.y;
            qf[qc][c][2] = (_Float16)a.z; qf[qc][c][3] = (_Float16)a.w;
            qf[qc][c][4] = (_Float16)b.x; qf[qc][c][5] = (_Float16)b.y;
            qf[qc][c][6] = (_Float16)b.z; qf[qc][c][7] = (_Float16)b.w;
        }
    }

    floatx4 ofrag[4][4];     // [qc][mc]
    #pragma unroll
    for (int qc = 0; qc < 4; ++qc)
        #pragma unroll
        for (int mc = 0; mc < 4; ++mc) ofrag[qc][mc] = floatx4{0.f, 0.f, 0.f, 0.f};
    float m_run[4] = {-1e30f, -1e30f, -1e30f, -1e30f};
    float l_run[4] = {0.f, 0.f, 0.f, 0.f};

    // staging: thread covers 32B of one row (two half8); 256 thr x 32B = 8KB
    const int srow = tid >> 2;          // 0..63
    const int sseg = (tid & 3) * 16;    // 0..48
    const _Float16* kgb = Kf + (((size_t)(bh * NL)) << 6) + (srow << 6) + sseg;     // + t*4096
    const _Float16* vgb = Vt + (((size_t)bh) << 17) + ((size_t)srow << 11) + sseg;  // + t*64
    _Float16* pbuf = Ps + w * 16 * PADQ;

    const int TB = 31 - 2 * pr;         // block stages tiles 0..TB (union)

    half8 kpre0 = *(const half8*)(kgb);
    half8 kpre1 = *(const half8*)(kgb + 8);
    half8 vpre0 = *(const half8*)(vgb);
    half8 vpre1 = *(const half8*)(vgb + 8);

    for (int t = 0; t <= TB; ++t) {
        const int j0 = t * 64;
        __syncthreads();                 // tile t-1 consumers done
        *(half8*)(Ks + srow * PADK + sseg)     = kpre0;
        *(half8*)(Ks + srow * PADK + sseg + 8) = kpre1;
        *(half8*)(Vs + srow * PADK + sseg)     = vpre0;
        *(half8*)(Vs + srow * PADK + sseg + 8) = vpre1;
        if (t < TB) {                    // prefetch next tile before barrier
            kpre0 = *(const half8*)(kgb + (t + 1) * 4096);
            kpre1 = *(const half8*)(kgb + (t + 1) * 4096 + 8);
            vpre0 = *(const half8*)(vgb + (t + 1) * 64);
            vpre1 = *(const half8*)(vgb + (t + 1) * 64 + 8);
        }
        __syncthreads();                 // tile t visible

        if (t > sa) continue;            // short waves idle (still stage above)

        // K and V fragments once per tile, shared by all 4 qcols
        half8 kfr[4][2], vfr[4][2];
        #pragma unroll
        for (int f = 0; f < 4; ++f) {
            kfr[f][0] = *(const half8*)(Ks + (f * 16 + col) * PADK + quad * 8);
            kfr[f][1] = *(const half8*)(Ks + (f * 16 + col) * PADK + 32 + quad * 8);
            vfr[f][0] = *(const half8*)(Vs + (f * 16 + col) * PADK + quad * 8);
            vfr[f][1] = *(const half8*)(Vs + (f * 16 + col) * PADK + 32 + quad * 8);
        }

        const bool diag = (t == sa);
        #pragma unroll
        for (int qc = 0; qc < 4; ++qc) {
            const int qrow = qbase + qc * 16 + col;

            // S^T = K * Q^T for this qcol
            floatx4 stf[4];
            #pragma unroll
            for (int f = 0; f < 4; ++f) {
                floatx4 acc = floatx4{0.f, 0.f, 0.f, 0.f};
                acc = __builtin_amdgcn_mfma_f32_16x16x32_f16(kfr[f][0], qf[qc][0], acc, 0, 0, 0);
                acc = __builtin_amdgcn_mfma_f32_16x16x32_f16(kfr[f][1], qf[qc][1], acc, 0, 0, 0);
                stf[f] = acc;
            }

            if (diag) {
                #pragma unroll
                for (int f = 0; f < 4; ++f)
                    #pragma unroll
                    for (int r = 0; r < 4; ++r) {
                        const int key = j0 + f * 16 + quad * 4 + r;
                        if (key > qrow) stf[f][r] = -1e30f;
                    }
            }

            // online softmax (per query column; partners col, col+16/32/48)
            float mt = -1e30f;
            #pragma unroll
            for (int f = 0; f < 4; ++f)
                #pragma unroll
                for (int r = 0; r < 4; ++r) mt = fmaxf(mt, stf[f][r]);
            mt = fmaxf(mt, __shfl_xor(mt, 16));
            mt = fmaxf(mt, __shfl_xor(mt, 32));
            const float m_new = fmaxf(m_run[qc], mt);
            const float alpha = __expf(m_run[qc] - m_new);
            float ls = 0.f;
            #pragma unroll
            for (int f = 0; f < 4; ++f)
                #pragma unroll
                for (int r = 0; r < 4; ++r) {
                    const float p = __expf(stf[f][r] - m_new);
                    stf[f][r] = p;
                    ls += p;
                }
            ls += __shfl_xor(ls, 16);
            ls += __shfl_xor(ls, 32);
            l_run[qc] = l_run[qc] * alpha + ls;
            m_run[qc] = m_new;
            #pragma unroll
            for (int mc = 0; mc < 4; ++mc) ofrag[qc][mc] *= alpha;

            // P^T via per-wave LDS round-trip (wave-private; wave-order safe)
            #pragma unroll
            for (int f = 0; f < 4; ++f) {
                half4 hp;
                hp[0] = (_Float16)stf[f][0]; hp[1] = (_Float16)stf[f][1];
                hp[2] = (_Float16)stf[f][2]; hp[3] = (_Float16)stf[f][3];
                *(half4*)(pbuf + col * PADQ + f * 16 + quad * 4) = hp;
            }
            half8 pf0 = *(const half8*)(pbuf + col * PADQ + quad * 8);
            half8 pf1 = *(const half8*)(pbuf + col * PADQ + 32 + quad * 8);

            // O^T += V^T * P^T
            #pragma unroll
            for (int mc = 0; mc < 4; ++mc) {
                ofrag[qc][mc] = __builtin_amdgcn_mfma_f32_16x16x32_f16(vfr[mc][0], pf0, ofrag[qc][mc], 0, 0, 0);
                ofrag[qc][mc] = __builtin_amdgcn_mfma_f32_16x16x32_f16(vfr[mc][1], pf1, ofrag[qc][mc], 0, 0, 0);
            }
        }
    }

    // epilogue: divide by l, store fp32. Out [B,H,L,D]
    #pragma unroll
    for (int qc = 0; qc < 4; ++qc) {
        const float inv = 1.f / l_run[qc];
        float* op = Og + ((size_t)bh * NL + qbase + qc * 16 + col) * ND;
        #pragma unroll
        for (int mc = 0; mc < 4; ++mc) {
            float4 o;
            o.x = ofrag[qc][mc][0] * inv;
            o.y = ofrag[qc][mc][1] * inv;
            o.z = ofrag[qc][mc][2] * inv;
            o.w = ofrag[qc][mc][3] * inv;
            *(float4*)(op + mc * 16 + quad * 4) = o;
        }
    }
}

// ===================== fallback (round-2 kernel, passed) =====================
__global__ __launch_bounds__(256)
void lsattn_fb(const float* __restrict__ Qg,
               const float* __restrict__ Kg,
               const float* __restrict__ Vg,
               float* __restrict__ Og) {
    __shared__ alignas(16) unsigned short Kh[64 * PADK];
    __shared__ alignas(16) unsigned short Kl[64 * PADK];
    __shared__ alignas(16) unsigned short Vh[64 * PADK];

    const int qt   = 31 - (int)blockIdx.x;
    const int bh   = blockIdx.y;
    const int tid  = threadIdx.x;
    const int lane = tid & 63;
    const int w    = tid >> 6;
    const int col  = lane & 15;
    const int quad = lane >> 4;
    const int qrow = qt * 64 + w * 16 + col;

    short8 qhi[2], qlo[2];
    {
        const float* qp = Qg + ((bh >> 4) * NL + qrow) * (NH * ND) + (bh & 15) * ND + quad * 8;
        #pragma unroll
        for (int c = 0; c < 2; ++c) {
            float qv[8];
            *(float4*)(qv + 0) = *(const float4*)(qp + c * 32);
            *(float4*)(qv + 4) = *(const float4*)(qp + c * 32 + 4);
            #pragma unroll
            for (int j = 0; j < 8; ++j) {
                unsigned short h = f2bf(qv[j]);
                qhi[c][j] = (short)h;
                qlo[c][j] = (short)f2bf(qv[j] - bf2f(h));
            }
        }
    }
    floatx4 ofrag[4];
    #pragma unroll
    for (int i = 0; i < 4; ++i) ofrag[i] = floatx4{0.f, 0.f, 0.f, 0.f};
    float m_run = -1e30f, l_run = 0.f;
    const int skey  = tid >> 2;
    const int sdb   = (tid & 3) * 16;
    const int gbase = (bh >> 4) * NL * NH * ND + (bh & 15) * ND;

    for (int t = 0; t <= qt; ++t) {
        const int j0 = t * 64;
        __syncthreads();
        {
            const int gro = gbase + (j0 + skey) * (NH * ND) + sdb;
            float kv[16], vv[16];
            #pragma unroll
            for (int i = 0; i < 16; i += 4) {
                *(float4*)(kv + i) = *(const float4*)(Kg + gro + i);
                *(float4*)(vv + i) = *(const float4*)(Vg + gro + i);
            }
            short8 h0, h1, l0, l1;
            #pragma unroll
            for (int j = 0; j < 8; ++j) {
                unsigned short h = f2bf(kv[j]);
                h0[j] = (short)h; l0[j] = (short)f2bf(kv[j] - bf2f(h));
                unsigned short g = f2bf(kv[8 + j]);
                h1[j] = (short)g; l1[j] = (short)f2bf(kv[8 + j] - bf2f(g));
            }
            *(short8*)(Kh + skey * PADK + sdb)     = h0;
            *(short8*)(Kh + skey * PADK + sdb + 8) = h1;
            *(short8*)(Kl + skey * PADK + sdb)     = l0;
            *(short8*)(Kl + skey * PADK + sdb + 8) = l1;
            #pragma unroll
            for (int i = 0; i < 16; ++i) Vh[(sdb + i) * PADK + skey] = f2bf(vv[i]);
        }
        __syncthreads();

        floatx4 stf[4];
        #pragma unroll
        for (int f = 0; f < 4; ++f) {
            floatx4 acc = floatx4{0.f, 0.f, 0.f, 0.f};
            #pragma unroll
            for (int c = 0; c < 2; ++c) {
                short8 kh = *(const short8*)(Kh + (f * 16 + col) * PADK + c * 32 + quad * 8);
                short8 kl = *(const short8*)(Kl + (f * 16 + col) * PADK + c * 32 + quad * 8);
                acc = __builtin_amdgcn_mfma_f32_16x16x32_bf16(kh, qhi[c], acc, 0, 0, 0);
                acc = __builtin_amdgcn_mfma_f32_16x16x32_bf16(kl, qhi[c], acc, 0, 0, 0);
                acc = __builtin_amdgcn_mfma_f32_16x16x32_bf16(kh, qlo[c], acc, 0, 0, 0);
            }
            stf[f] = acc;
        }
        if (t == qt) {
            #pragma unroll
            for (int f = 0; f < 4; ++f)
                #pragma unroll
                for (int r = 0; r < 4; ++r) {
                    const int key = j0 + f * 16 + quad * 4 + r;
                    if (key > qrow) stf[f][r] = -1e30f;
                }
        }
        float mt = -1e30f;
        #pragma unroll
        for (int f = 0; f < 4; ++f)
            #pragma unroll
            for (int r = 0; r < 4; ++r) mt = fmaxf(mt, stf[f][r]);
        mt = fmaxf(mt, __shfl_xor(mt, 16));
        mt = fmaxf(mt, __shfl_xor(mt, 32));
        const float m_new = fmaxf(m_run, mt);
        const float alpha = __expf(m_run - m_new);
        float ls = 0.f;
        #pragma unroll
        for (int f = 0; f < 4; ++f)
            #pragma unroll
            for (int r = 0; r < 4; ++r) {
                const float p = __expf(stf[f][r] - m_new);
                stf[f][r] = p; ls += p;
            }
        ls += __shfl_xor(ls, 16);
        ls += __shfl_xor(ls, 32);
        l_run = l_run * alpha + ls;
        m_run = m_new;
        #pragma unroll
        for (int mc = 0; mc < 4; ++mc) ofrag[mc] *= alpha;

        short8 pfrag[2];
        #pragma unroll
        for (int kc = 0; kc < 2; ++kc) {
            #pragma unroll
            for (int jj = 0; jj < 8; ++jj) {
                const int r  = jj & 3;
                const int sq = (quad & 1) * 2 + (jj >> 2);
                const int sl = col + (sq << 4);
                const float va = __shfl(stf[kc * 2 + 0][r], sl);
                const float vb = __shfl(stf[kc * 2 + 1][r], sl);
                pfrag[kc][jj] = (short)f2bf((quad & 2) ? vb : va);
            }
        }
        #pragma unroll
        for (int mc = 0; mc < 4; ++mc) {
            #pragma unroll
            for (int kc = 0; kc < 2; ++kc) {
                short8 vf = *(const short8*)(Vh + (mc * 16 + col) * PADK + kc * 32 + quad * 8);
                ofrag[mc] = __builtin_amdgcn_mfma_f32_16x16x32_bf16(vf, pfrag[kc], ofrag[mc], 0, 0, 0);
            }
        }
    }
    const float inv = 1.f / l_run;
    float* op = Og + ((size_t)bh * NL + qrow) * ND;
    #pragma unroll
    for (int mc = 0; mc < 4; ++mc) {
        float4 o;
        o.x = ofrag[mc][0] * inv; o.y = ofrag[mc][1] * inv;
        o.z = ofrag[mc][2] * inv; o.w = ofrag[mc][3] * inv;
        *(float4*)(op + mc * 16 + quad * 4) = o;
    }
}

extern "C" void kernel_launch(void* const* d_in, const int* in_sizes, int n_in,
                              void* d_out, int out_size, void* d_ws, size_t ws_size,
                              hipStream_t stream) {
    const float* Q = (const float*)d_in[0];
    const float* K = (const float*)d_in[1];
    const float* V = (const float*)d_in[2];
    float* O = (float*)d_out;

    const size_t elems = (size_t)NB * NL * NH * ND;          // 8,388,608
    if (ws_size >= 2 * elems * sizeof(_Float16)) {           // 32 MiB needed
        _Float16* Kf = (_Float16*)d_ws;
        _Float16* Vt = Kf + elems;
        conv_kv<<<dim3(32, 64), dim3(256), 0, stream>>>(K, V, Kf, Vt);
        lsattn_main<<<dim3(512), dim3(256), 0, stream>>>(Q, Kf, Vt, O);
    } else {
        lsattn_fb<<<dim3(32, 64), dim3(256), 0, stream>>>(Q, K, V, O);
    }
}

// Round 7
// 200.608 us; speedup vs baseline: 1.0752x; 1.0752x over previous
//
#include <hip/hip_runtime.h>

// logsparseAttention == plain CAUSAL attention (no scale) at L=2048, SUB_LEN=5.
// Q,K,V [B,L,H,D] fp32; Out [B,H,L,D] fp32.  B=4, L=2048, H=16, D=64.
// R7: VALU-busy-driven hybrid. Evidence (R5 vs R6): VALU work ~35us and MFMA
// ~14us are invariant; dur = VALU/VALUBusy. R6 lost concurrency (2 waves/SIMD)
// and serialized qcols on a shared P buffer (WAR). R7: 2 qcols/wave with
// PRIVATE per-(wave,qcol) P buffers (independent chains), 4-wave/256-thr
// blocks, grid 1024 -> 4 blocks/CU = 4 waves/SIMD, K/V frags shared by both
// qcols. Pairing waves 0-1 -> supertile pr, 2-3 -> 31-pr: all blocks equal.

typedef __attribute__((ext_vector_type(8))) short short8;
typedef __attribute__((ext_vector_type(4))) float floatx4;
typedef _Float16 half8 __attribute__((ext_vector_type(8)));
typedef _Float16 half4 __attribute__((ext_vector_type(4)));

#define NB 4
#define NL 2048
#define NH 16
#define ND 64
#define PADK 72   // halves; 144B row stride
#define PADQ 72

static __device__ __forceinline__ unsigned short f2bf(float f) {
    unsigned int u = __float_as_uint(f);
    u += 0x7fff + ((u >> 16) & 1);
    return (unsigned short)(u >> 16);
}
static __device__ __forceinline__ float bf2f(unsigned short h) {
    return __uint_as_float(((unsigned int)h) << 16);
}

// ---- fused prepass: K -> Kf [bh][key][d] fp16; V -> Vt [bh][d][key] fp16 ----
__global__ __launch_bounds__(256)
void conv_kv(const float* __restrict__ Kg, const float* __restrict__ Vg,
             _Float16* __restrict__ Kf, _Float16* __restrict__ Vt) {
    __shared__ float tile[64][65];
    const int kt = blockIdx.x;       // key tile 0..31
    const int bh = blockIdx.y;       // 0..63
    const int b  = bh >> 4, h = bh & 15;
    const int t  = threadIdx.x;
    const int row = t >> 2;          // 0..63
    const int seg = (t & 3) * 16;    // 0..48
    const size_t gsrc = (((size_t)(b * NL + kt * 64 + row) * NH + h) << 6) + seg;
    {   // K: straight vectorized convert
        float kv[16];
        #pragma unroll
        for (int i = 0; i < 16; i += 4) *(float4*)(kv + i) = *(const float4*)(Kg + gsrc + i);
        half8 o0, o1;
        #pragma unroll
        for (int j2 = 0; j2 < 8; ++j2) { o0[j2] = (_Float16)kv[j2]; o1[j2] = (_Float16)kv[8 + j2]; }
        _Float16* kd = Kf + (((size_t)(bh * NL + kt * 64 + row)) << 6) + seg;
        *(half8*)kd = o0;
        *(half8*)(kd + 8) = o1;
    }
    {   // V phase 1: fp32 tile into LDS
        #pragma unroll
        for (int i = 0; i < 16; i += 4) {
            float4 v = *(const float4*)(Vg + gsrc + i);
            tile[row][seg + i + 0] = v.x;
            tile[row][seg + i + 1] = v.y;
            tile[row][seg + i + 2] = v.z;
            tile[row][seg + i + 3] = v.w;
        }
    }
    __syncthreads();
    #pragma unroll
    for (int pass = 0; pass < 2; ++pass) {   // V phase 2: transpose out as fp16
        const int d  = pass * 32 + (t >> 3);
        const int kk = (t & 7) * 8;
        half8 o;
        #pragma unroll
        for (int j2 = 0; j2 < 8; ++j2) o[j2] = (_Float16)tile[kk + j2][d];
        *(half8*)(Vt + (((size_t)(bh * 64 + d)) << 11) + kt * 64 + kk) = o;
    }
}

// ------------------------------- main kernel --------------------------------
__global__ __launch_bounds__(256, 4)
void lsattn_main(const float* __restrict__ Qg,
                 const _Float16* __restrict__ Kf,
                 const _Float16* __restrict__ Vt,
                 float* __restrict__ Og) {
    __shared__ alignas(16) _Float16 Ks[64 * PADK];          // [key][d]     9216B
    __shared__ alignas(16) _Float16 Vs[64 * PADK];          // [d][key]     9216B
    __shared__ alignas(16) _Float16 Ps[8 * 16 * PADQ];      // (w,qc) bufs 18432B

    const int id   = (int)blockIdx.x;        // 0..1023
    const int bh   = id & 63;
    const int pr   = id >> 6;                // 0..15
    const int tid  = threadIdx.x;
    const int lane = tid & 63;
    const int w    = tid >> 6;               // wave 0..3
    const int col  = lane & 15;
    const int quad = lane >> 4;

    // waves 0-1 -> 64q supertile pr, waves 2-3 -> 31-pr; wave owns 32 q
    const int s64   = (w < 2) ? pr : (31 - pr);
    const int qbase = s64 * 64 + (w & 1) * 32;
    const int sa    = s64;                   // wave's last key tile

    // Q fragments for 2 qcols, B-operand layout
    half8 qf[2][2];
    #pragma unroll
    for (int qc = 0; qc < 2; ++qc) {
        const float* qp = Qg + (((size_t)((bh >> 4) * NL + qbase + qc * 16 + col) * NH + (bh & 15)) << 6) + quad * 8;
        #pragma unroll
        for (int c = 0; c < 2; ++c) {
            float4 a = *(const float4*)(qp + c * 32);
            float4 b = *(const float4*)(qp + c * 32 + 4);
            qf[qc][c][0] = (_Float16)a.x; qf[qc][c][1] = (_Float16)a.y;
            qf[qc][c][2] = (_Float16)a.z; qf[qc][c][3] = (_Float16)a.w;
            qf[qc][c][4] = (_Float16)b.x; qf[qc][c][5] = (_Float16)b.y;
            qf[qc][c][6] = (_Float16)b.z; qf[qc][c][7] = (_Float16)b.w;
        }
    }

    floatx4 ofrag[2][4];     // [qc][mc]
    #pragma unroll
    for (int qc = 0; qc < 2; ++qc)
        #pragma unroll
        for (int mc = 0; mc < 4; ++mc) ofrag[qc][mc] = floatx4{0.f, 0.f, 0.f, 0.f};
    float m_run[2] = {-1e30f, -1e30f};
    float l_run[2] = {0.f, 0.f};

    // staging: thread covers 32B of one row; 256 thr x 32B = 8KB per buffer
    const int srow = tid >> 2;          // 0..63
    const int sseg = (tid & 3) * 16;    // 0..48
    const _Float16* kgb = Kf + (((size_t)(bh * NL)) << 6) + (srow << 6) + sseg;     // + t*4096
    const _Float16* vgb = Vt + (((size_t)bh) << 17) + ((size_t)srow << 11) + sseg;  // + t*64
    _Float16* pbuf0 = Ps + (w * 2 + 0) * 16 * PADQ;   // private per (wave,qc)
    _Float16* pbuf1 = Ps + (w * 2 + 1) * 16 * PADQ;

    const int TB = 31 - pr;             // block stages tiles 0..TB (union)

    half8 kpre0 = *(const half8*)(kgb);
    half8 kpre1 = *(const half8*)(kgb + 8);
    half8 vpre0 = *(const half8*)(vgb);
    half8 vpre1 = *(const half8*)(vgb + 8);

    for (int t = 0; t <= TB; ++t) {
        const int j0 = t * 64;
        __syncthreads();                 // tile t-1 consumers done
        *(half8*)(Ks + srow * PADK + sseg)     = kpre0;
        *(half8*)(Ks + srow * PADK + sseg + 8) = kpre1;
        *(half8*)(Vs + srow * PADK + sseg)     = vpre0;
        *(half8*)(Vs + srow * PADK + sseg + 8) = vpre1;
        if (t < TB) {                    // prefetch next tile before barrier
            kpre0 = *(const half8*)(kgb + (t + 1) * 4096);
            kpre1 = *(const half8*)(kgb + (t + 1) * 4096 + 8);
            vpre0 = *(const half8*)(vgb + (t + 1) * 64);
            vpre1 = *(const half8*)(vgb + (t + 1) * 64 + 8);
        }
        __syncthreads();                 // tile t visible

        if (t > sa) continue;            // short waves idle (still stage above)

        // S^T = K * Q^T for both qcols; K fragments read once, shared
        floatx4 stf0[4], stf1[4];
        {
            #pragma unroll
            for (int f = 0; f < 4; ++f) {
                half8 k0 = *(const half8*)(Ks + (f * 16 + col) * PADK + quad * 8);
                half8 k1 = *(const half8*)(Ks + (f * 16 + col) * PADK + 32 + quad * 8);
                floatx4 a0 = floatx4{0.f, 0.f, 0.f, 0.f};
                a0 = __builtin_amdgcn_mfma_f32_16x16x32_f16(k0, qf[0][0], a0, 0, 0, 0);
                a0 = __builtin_amdgcn_mfma_f32_16x16x32_f16(k1, qf[0][1], a0, 0, 0, 0);
                stf0[f] = a0;
                floatx4 a1 = floatx4{0.f, 0.f, 0.f, 0.f};
                a1 = __builtin_amdgcn_mfma_f32_16x16x32_f16(k0, qf[1][0], a1, 0, 0, 0);
                a1 = __builtin_amdgcn_mfma_f32_16x16x32_f16(k1, qf[1][1], a1, 0, 0, 0);
                stf1[f] = a1;
            }
        }

        if (t == sa) {                   // causal mask on the diagonal tile
            #pragma unroll
            for (int f = 0; f < 4; ++f)
                #pragma unroll
                for (int r = 0; r < 4; ++r) {
                    const int key = j0 + f * 16 + quad * 4 + r;
                    if (key > qbase + col)      stf0[f][r] = -1e30f;
                    if (key > qbase + 16 + col) stf1[f][r] = -1e30f;
                }
        }

        // online softmax — two independent chains (qc0, qc1)
        float mt0 = -1e30f, mt1 = -1e30f;
        #pragma unroll
        for (int f = 0; f < 4; ++f)
            #pragma unroll
            for (int r = 0; r < 4; ++r) {
                mt0 = fmaxf(mt0, stf0[f][r]);
                mt1 = fmaxf(mt1, stf1[f][r]);
            }
        mt0 = fmaxf(mt0, __shfl_xor(mt0, 16));
        mt1 = fmaxf(mt1, __shfl_xor(mt1, 16));
        mt0 = fmaxf(mt0, __shfl_xor(mt0, 32));
        mt1 = fmaxf(mt1, __shfl_xor(mt1, 32));
        const float mn0 = fmaxf(m_run[0], mt0);
        const float mn1 = fmaxf(m_run[1], mt1);
        const float al0 = __expf(m_run[0] - mn0);
        const float al1 = __expf(m_run[1] - mn1);
        float ls0 = 0.f, ls1 = 0.f;
        #pragma unroll
        for (int f = 0; f < 4; ++f)
            #pragma unroll
            for (int r = 0; r < 4; ++r) {
                const float p0 = __expf(stf0[f][r] - mn0);
                const float p1 = __expf(stf1[f][r] - mn1);
                stf0[f][r] = p0; ls0 += p0;
                stf1[f][r] = p1; ls1 += p1;
            }
        ls0 += __shfl_xor(ls0, 16);
        ls1 += __shfl_xor(ls1, 16);
        ls0 += __shfl_xor(ls0, 32);
        ls1 += __shfl_xor(ls1, 32);
        l_run[0] = l_run[0] * al0 + ls0;  m_run[0] = mn0;
        l_run[1] = l_run[1] * al1 + ls1;  m_run[1] = mn1;
        #pragma unroll
        for (int mc = 0; mc < 4; ++mc) { ofrag[0][mc] *= al0; ofrag[1][mc] *= al1; }

        // P^T via LDS round-trip — PRIVATE buffer per qc (no WAR coupling)
        #pragma unroll
        for (int f = 0; f < 4; ++f) {
            half4 h0, h1;
            h0[0] = (_Float16)stf0[f][0]; h0[1] = (_Float16)stf0[f][1];
            h0[2] = (_Float16)stf0[f][2]; h0[3] = (_Float16)stf0[f][3];
            h1[0] = (_Float16)stf1[f][0]; h1[1] = (_Float16)stf1[f][1];
            h1[2] = (_Float16)stf1[f][2]; h1[3] = (_Float16)stf1[f][3];
            *(half4*)(pbuf0 + col * PADQ + f * 16 + quad * 4) = h0;
            *(half4*)(pbuf1 + col * PADQ + f * 16 + quad * 4) = h1;
        }
        half8 pf00 = *(const half8*)(pbuf0 + col * PADQ + quad * 8);
        half8 pf01 = *(const half8*)(pbuf0 + col * PADQ + 32 + quad * 8);
        half8 pf10 = *(const half8*)(pbuf1 + col * PADQ + quad * 8);
        half8 pf11 = *(const half8*)(pbuf1 + col * PADQ + 32 + quad * 8);

        // O^T += V^T * P^T; V fragments read once (after K frags are dead)
        #pragma unroll
        for (int mc = 0; mc < 4; ++mc) {
            half8 v0 = *(const half8*)(Vs + (mc * 16 + col) * PADK + quad * 8);
            half8 v1 = *(const half8*)(Vs + (mc * 16 + col) * PADK + 32 + quad * 8);
            ofrag[0][mc] = __builtin_amdgcn_mfma_f32_16x16x32_f16(v0, pf00, ofrag[0][mc], 0, 0, 0);
            ofrag[0][mc] = __builtin_amdgcn_mfma_f32_16x16x32_f16(v1, pf01, ofrag[0][mc], 0, 0, 0);
            ofrag[1][mc] = __builtin_amdgcn_mfma_f32_16x16x32_f16(v0, pf10, ofrag[1][mc], 0, 0, 0);
            ofrag[1][mc] = __builtin_amdgcn_mfma_f32_16x16x32_f16(v1, pf11, ofrag[1][mc], 0, 0, 0);
        }
    }

    // epilogue: divide by l, store fp32. Out [B,H,L,D]
    #pragma unroll
    for (int qc = 0; qc < 2; ++qc) {
        const float inv = 1.f / l_run[qc];
        float* op = Og + ((size_t)bh * NL + qbase + qc * 16 + col) * ND;
        #pragma unroll
        for (int mc = 0; mc < 4; ++mc) {
            float4 o;
            o.x = ofrag[qc][mc][0] * inv;
            o.y = ofrag[qc][mc][1] * inv;
            o.z = ofrag[qc][mc][2] * inv;
            o.w = ofrag[qc][mc][3] * inv;
            *(float4*)(op + mc * 16 + quad * 4) = o;
        }
    }
}

// ===================== fallback (round-2 kernel, passed) =====================
__global__ __launch_bounds__(256)
void lsattn_fb(const float* __restrict__ Qg,
               const float* __restrict__ Kg,
               const float* __restrict__ Vg,
               float* __restrict__ Og) {
    __shared__ alignas(16) unsigned short Kh[64 * PADK];
    __shared__ alignas(16) unsigned short Kl[64 * PADK];
    __shared__ alignas(16) unsigned short Vh[64 * PADK];

    const int qt   = 31 - (int)blockIdx.x;
    const int bh   = blockIdx.y;
    const int tid  = threadIdx.x;
    const int lane = tid & 63;
    const int w    = tid >> 6;
    const int col  = lane & 15;
    const int quad = lane >> 4;
    const int qrow = qt * 64 + w * 16 + col;

    short8 qhi[2], qlo[2];
    {
        const float* qp = Qg + ((bh >> 4) * NL + qrow) * (NH * ND) + (bh & 15) * ND + quad * 8;
        #pragma unroll
        for (int c = 0; c < 2; ++c) {
            float qv[8];
            *(float4*)(qv + 0) = *(const float4*)(qp + c * 32);
            *(float4*)(qv + 4) = *(const float4*)(qp + c * 32 + 4);
            #pragma unroll
            for (int j = 0; j < 8; ++j) {
                unsigned short h = f2bf(qv[j]);
                qhi[c][j] = (short)h;
                qlo[c][j] = (short)f2bf(qv[j] - bf2f(h));
            }
        }
    }
    floatx4 ofrag[4];
    #pragma unroll
    for (int i = 0; i < 4; ++i) ofrag[i] = floatx4{0.f, 0.f, 0.f, 0.f};
    float m_run = -1e30f, l_run = 0.f;
    const int skey  = tid >> 2;
    const int sdb   = (tid & 3) * 16;
    const int gbase = (bh >> 4) * NL * NH * ND + (bh & 15) * ND;

    for (int t = 0; t <= qt; ++t) {
        const int j0 = t * 64;
        __syncthreads();
        {
            const int gro = gbase + (j0 + skey) * (NH * ND) + sdb;
            float kv[16], vv[16];
            #pragma unroll
            for (int i = 0; i < 16; i += 4) {
                *(float4*)(kv + i) = *(const float4*)(Kg + gro + i);
                *(float4*)(vv + i) = *(const float4*)(Vg + gro + i);
            }
            short8 h0, h1, l0, l1;
            #pragma unroll
            for (int j = 0; j < 8; ++j) {
                unsigned short h = f2bf(kv[j]);
                h0[j] = (short)h; l0[j] = (short)f2bf(kv[j] - bf2f(h));
                unsigned short g = f2bf(kv[8 + j]);
                h1[j] = (short)g; l1[j] = (short)f2bf(kv[8 + j] - bf2f(g));
            }
            *(short8*)(Kh + skey * PADK + sdb)     = h0;
            *(short8*)(Kh + skey * PADK + sdb + 8) = h1;
            *(short8*)(Kl + skey * PADK + sdb)     = l0;
            *(short8*)(Kl + skey * PADK + sdb + 8) = l1;
            #pragma unroll
            for (int i = 0; i < 16; ++i) Vh[(sdb + i) * PADK + skey] = f2bf(vv[i]);
        }
        __syncthreads();

        floatx4 stf[4];
        #pragma unroll
        for (int f = 0; f < 4; ++f) {
            floatx4 acc = floatx4{0.f, 0.f, 0.f, 0.f};
            #pragma unroll
            for (int c = 0; c < 2; ++c) {
                short8 kh = *(const short8*)(Kh + (f * 16 + col) * PADK + c * 32 + quad * 8);
                short8 kl = *(const short8*)(Kl + (f * 16 + col) * PADK + c * 32 + quad * 8);
                acc = __builtin_amdgcn_mfma_f32_16x16x32_bf16(kh, qhi[c], acc, 0, 0, 0);
                acc = __builtin_amdgcn_mfma_f32_16x16x32_bf16(kl, qhi[c], acc, 0, 0, 0);
                acc = __builtin_amdgcn_mfma_f32_16x16x32_bf16(kh, qlo[c], acc, 0, 0, 0);
            }
            stf[f] = acc;
        }
        if (t == qt) {
            #pragma unroll
            for (int f = 0; f < 4; ++f)
                #pragma unroll
                for (int r = 0; r < 4; ++r) {
                    const int key = j0 + f * 16 + quad * 4 + r;
                    if (key > qrow) stf[f][r] = -1e30f;
                }
        }
        float mt = -1e30f;
        #pragma unroll
        for (int f = 0; f < 4; ++f)
            #pragma unroll
            for (int r = 0; r < 4; ++r) mt = fmaxf(mt, stf[f][r]);
        mt = fmaxf(mt, __shfl_xor(mt, 16));
        mt = fmaxf(mt, __shfl_xor(mt, 32));
        const float m_new = fmaxf(m_run, mt);
        const float alpha = __expf(m_run - m_new);
        float ls = 0.f;
        #pragma unroll
        for (int f = 0; f < 4; ++f)
            #pragma unroll
            for (int r = 0; r < 4; ++r) {
                const float p = __expf(stf[f][r] - m_new);
                stf[f][r] = p; ls += p;
            }
        ls += __shfl_xor(ls, 16);
        ls += __shfl_xor(ls, 32);
        l_run = l_run * alpha + ls;
        m_run = m_new;
        #pragma unroll
        for (int mc = 0; mc < 4; ++mc) ofrag[mc] *= alpha;

        short8 pfrag[2];
        #pragma unroll
        for (int kc = 0; kc < 2; ++kc) {
            #pragma unroll
            for (int jj = 0; jj < 8; ++jj) {
                const int r  = jj & 3;
                const int sq = (quad & 1) * 2 + (jj >> 2);
                const int sl = col + (sq << 4);
                const float va = __shfl(stf[kc * 2 + 0][r], sl);
                const float vb = __shfl(stf[kc * 2 + 1][r], sl);
                pfrag[kc][jj] = (short)f2bf((quad & 2) ? vb : va);
            }
        }
        #pragma unroll
        for (int mc = 0; mc < 4; ++mc) {
            #pragma unroll
            for (int kc = 0; kc < 2; ++kc) {
                short8 vf = *(const short8*)(Vh + (mc * 16 + col) * PADK + kc * 32 + quad * 8);
                ofrag[mc] = __builtin_amdgcn_mfma_f32_16x16x32_bf16(vf, pfrag[kc], ofrag[mc], 0, 0, 0);
            }
        }
    }
    const float inv = 1.f / l_run;
    float* op = Og + ((size_t)bh * NL + qrow) * ND;
    #pragma unroll
    for (int mc = 0; mc < 4; ++mc) {
        float4 o;
        o.x = ofrag[mc][0] * inv; o.y = ofrag[mc][1] * inv;
        o.z = ofrag[mc][2] * inv; o.w = ofrag[mc][3] * inv;
        *(float4*)(op + mc * 16 + quad * 4) = o;
    }
}

extern "C" void kernel_launch(void* const* d_in, const int* in_sizes, int n_in,
                              void* d_out, int out_size, void* d_ws, size_t ws_size,
                              hipStream_t stream) {
    const float* Q = (const float*)d_in[0];
    const float* K = (const float*)d_in[1];
    const float* V = (const float*)d_in[2];
    float* O = (float*)d_out;

    const size_t elems = (size_t)NB * NL * NH * ND;          // 8,388,608
    if (ws_size >= 2 * elems * sizeof(_Float16)) {           // 32 MiB needed
        _Float16* Kf = (_Float16*)d_ws;
        _Float16* Vt = Kf + elems;
        conv_kv<<<dim3(32, 64), dim3(256), 0, stream>>>(K, V, Kf, Vt);
        lsattn_main<<<dim3(1024), dim3(256), 0, stream>>>(Q, Kf, Vt, O);
    } else {
        lsattn_fb<<<dim3(32, 64), dim3(256), 0, stream>>>(Q, K, V, O);
    }
}